// Round 8
// baseline (30414.050 us; speedup 1.0000x reference)
//
#include <hip/hip_runtime.h>

// ---------------------------------------------------------------------------
// Memory-network forward, fp32-exact (r8: GRU = 4 blocks/chain x 768 thr,
// 192 rows/block, 64 weight-VGPRs/lane pinned via inline asm, double-buffered
// G + monotonic counter step-sync). B=32, MEM=50, SEN=QLEN=20, H=256.
// ---------------------------------------------------------------------------

#define TPB 256
#define NB    32
#define MEMN  50
#define SEN   20
#define VOC   100000
#define SEQEND_TOK 2
#define GBLK  4            // GRU blocks per chain
#define GTHR  768          // threads per GRU block
#define GROWS 192          // gate-rows per GRU block

// ---- workspace layout (float offsets) ----
#define GI_OFF    0
#define KVB_OFF   0            // [1600][512] k|v projections (alias, after gi dead)
#define MB_OFF    819200       // [32][3][256] hop outputs
#define T1_OFF    843776       // [288][768]
#define T2_OFF    1064960      // [288][768]
#define RS_OFF    1286144      // [32][768]
#define WTIH_OFF  25067520     // w_ih^T [256][768]
#define WTHH_OFF  25264128     // w_hh^T [256][768]
#define KVT_OFF   25460736     // [256][512] = [wk^T | wv^T]
#define WQT_OFF   25591808     // [256][256]
#define WOT_OFF   25657344
#define F1T_OFF   25722880
#define F2T_OFF   25788416
#define G1T_OFF   25853952     // g_w1^T [768][768]
#define G2T_OFF   26443776
#define BKV_OFF   27033600     // [512] = bk|bv
#define IDX_OFF   27034112     // 1600 sidx + 32 qidx (ints)
#define SLOT_OFF  27035744     // [32][50][256] memory slots
#define RQ_OFF    27445344     // [32][256] real query
#define G_OFF     27453536     // story gate buffer [50][2][768]
#define GQ_OFF    27530336     // query gate buffer [32][2][768]
#define SCNT_OFF  27579488     // 50 story + 32 query uint counters

// ---------------------------------------------------------------------------
// Setup: transposes to k-major, bias concat, SEQEND index scan, counter zero.
// ---------------------------------------------------------------------------
__global__ void k_setup(const float* __restrict__ w_ih, const float* __restrict__ w_hh,
                        const float* __restrict__ wk,  const float* __restrict__ wv,
                        const float* __restrict__ wq,  const float* __restrict__ wo,
                        const float* __restrict__ f1,  const float* __restrict__ f2,
                        const float* __restrict__ g1,  const float* __restrict__ g2,
                        const float* __restrict__ bk,  const float* __restrict__ bv,
                        const int* __restrict__ story, const int* __restrict__ query,
                        float* __restrict__ ws)
{
  int g = blockIdx.x * TPB + threadIdx.x;
  if (g < 196608) { int j = g >> 8, k = g & 255; ws[WTIH_OFF + k*768 + j] = w_ih[g]; return; }
  g -= 196608;
  if (g < 196608) { int j = g >> 8, k = g & 255; ws[WTHH_OFF + k*768 + j] = w_hh[g]; return; }
  g -= 196608;
  if (g < 65536) { int j = g >> 8, k = g & 255; ws[KVT_OFF + k*512 + j] = wk[g]; return; }
  g -= 65536;
  if (g < 65536) { int j = g >> 8, k = g & 255; ws[KVT_OFF + k*512 + 256 + j] = wv[g]; return; }
  g -= 65536;
  if (g < 65536) { int j = g >> 8, k = g & 255; ws[WQT_OFF + k*256 + j] = wq[g]; return; }
  g -= 65536;
  if (g < 65536) { int j = g >> 8, k = g & 255; ws[WOT_OFF + k*256 + j] = wo[g]; return; }
  g -= 65536;
  if (g < 65536) { int j = g >> 8, k = g & 255; ws[F1T_OFF + k*256 + j] = f1[g]; return; }
  g -= 65536;
  if (g < 65536) { int j = g >> 8, k = g & 255; ws[F2T_OFF + k*256 + j] = f2[g]; return; }
  g -= 65536;
  if (g < 589824) { int j = g / 768, k = g - j*768; ws[G1T_OFF + k*768 + j] = g1[g]; return; }
  g -= 589824;
  if (g < 589824) { int j = g / 768, k = g - j*768; ws[G2T_OFF + k*768 + j] = g2[g]; return; }
  g -= 589824;
  if (g < 512) { ws[BKV_OFF + g] = (g < 256) ? bk[g] : bv[g - 256]; return; }
  g -= 512;
  if (g < 1600) {
    const int* st = story + g * SEN;
    int idx = SEN - 1;
    for (int t = 0; t < SEN; ++t) { if (st[t] == SEQEND_TOK) { idx = t; break; } }
    ((int*)(ws + IDX_OFF))[g] = idx;
    return;
  }
  g -= 1600;
  if (g < 32) {
    const int* qt = query + g * SEN;
    int idx = SEN - 1;
    for (int t = 0; t < SEN; ++t) { if (qt[t] == SEQEND_TOK) { idx = t; break; } }
    ((int*)(ws + IDX_OFF))[1600 + g] = idx;
    return;
  }
  g -= 32;
  if (g < 82) ((unsigned int*)(ws + SCNT_OFF))[g] = 0u;   // step counters
}

// ---------------------------------------------------------------------------
// Generic fp32 tiled GEMM: C[M][N] = gatherA[M][K] @ B(k-major [K][N]) + bias
// BM x 128 tile, BK=32, 256 threads. MODE 0: plain A; MODE 1: embedding
// gather; MODE 2: reason-combined gather.
// ---------------------------------------------------------------------------
template<int MODE, int BM>
__global__ __launch_bounds__(256) void k_gemm(
    const float* __restrict__ A, const float* __restrict__ B,
    const float* __restrict__ bias, float* __restrict__ C,
    int M, int N, int K, int relu,
    const int* __restrict__ tokS, const int* __restrict__ tokQ,
    const float* __restrict__ embed,
    const float* __restrict__ mbp, const float* __restrict__ rqp)
{
  __shared__ float At[BM * 33];
  __shared__ float Bt[128 * 33];
  constexpr int R = BM / 16;
  const int m0 = blockIdx.x * BM, n0 = blockIdx.y * 128;
  const int tx = threadIdx.x & 15, ty = threadIdx.x >> 4;
  float acc[R][8] = {};

  for (int k0 = 0; k0 < K; k0 += 32) {
    for (int idx = threadIdx.x; idx < BM * 32; idx += 256) {
      int r = idx >> 5, kk = idx & 31;
      int row = m0 + r, kg = k0 + kk;
      float v = 0.f;
      if (MODE == 1) {
        int tok = (row < 32000) ? tokS[row] : tokQ[row - 32000];
        v = embed[(size_t)tok * 256 + kg];
      } else if (MODE == 2) {
        if (row < 288) {
          int b = row / 9, p = row - b * 9;
          v = (kg < 256) ? mbp[(b*3 + (p % 3))*256 + kg]
            : (kg < 512) ? mbp[(b*3 + (p / 3))*256 + (kg - 256)]
                         : rqp[b*256 + (kg - 512)];
        }
      } else {
        if (row < M) v = A[(size_t)row * K + kg];
      }
      At[r * 33 + kk] = v;
    }
    for (int idx = threadIdx.x; idx < 4096; idx += 256) {
      int jj = idx & 127, kk = idx >> 7;
      Bt[jj * 33 + kk] = B[(k0 + kk) * N + n0 + jj];
    }
    __syncthreads();
#pragma unroll
    for (int kk = 0; kk < 32; ++kk) {
      float a[R], bb[8];
#pragma unroll
      for (int i = 0; i < R; ++i) a[i] = At[(i * 16 + ty) * 33 + kk];
#pragma unroll
      for (int i = 0; i < 8; ++i) bb[i] = Bt[(i * 16 + tx) * 33 + kk];
#pragma unroll
      for (int i = 0; i < R; ++i)
#pragma unroll
        for (int j2 = 0; j2 < 8; ++j2) acc[i][j2] += a[i] * bb[j2];
    }
    __syncthreads();
  }
#pragma unroll
  for (int i = 0; i < R; ++i) {
    int row = m0 + i * 16 + ty;
    if (row >= M) continue;
#pragma unroll
    for (int j2 = 0; j2 < 8; ++j2) {
      int col = n0 + j2 * 16 + tx;
      float v = acc[i][j2] + bias[col];
      if (relu) v = fmaxf(v, 0.f);
      C[(size_t)row * N + col] = v;
    }
  }
}

// ---------------------------------------------------------------------------
// GRU, 4 blocks per chain, 768 threads each. Grid = 200 blocks.
// Block (c,p): gate-rows [p*192, p*192+192). Thread (q = tid/192,
// r = tid%192): cols [q*64, q*64+64) of row rowbase+r -> 16 float4 = 64
// weight VGPRs, preloaded COALESCED from w_hh^T, PINNED via inline asm
// (blocks the r5 load-resink: asm may modify values, reload is illegal).
// regsPerBlock=131072 / 768 thr = 170 VGPR cap -> comfortable.
// h[256] in LDS; reads are wave-uniform b128 broadcasts (192 = 3 waves,
// q uniform per wave). Per step: 64 FMAs -> 4-way LDS reduce -> post
// 192-row slice to G[c][sigma&1] -> fence/barrier -> release-count ->
// spin to 4*sigma -> all 4 blocks redundantly combine (bitwise-identical).
// gi staged per-20-step chunk in LDS. 96 KB LDS pad -> 1 block/CU.
// ---------------------------------------------------------------------------
__global__ __launch_bounds__(GTHR, 1) void k_gru(
    const float* __restrict__ gi, const float* __restrict__ wT,
    const float* __restrict__ b_hh, const int* __restrict__ idxI,
    float* __restrict__ slot_out, float* __restrict__ rq_out,
    float* __restrict__ G, float* __restrict__ GQ,
    unsigned int* __restrict__ scnt, unsigned int* __restrict__ qcnt)
{
  __shared__ __align__(16) float smem[24576];   // 96 KB -> 1 block/CU
  float* hs     = smem;          // [256]
  float* part   = smem + 256;    // [768]
  float* st_own = smem + 1024;   // [20][192] own-rows gi (rows < 512 only)
  float* st_gn  = smem + 4864;   // [20][256] n-gate gi

  const int c = blockIdx.x / GBLK;
  const int p = blockIdx.x - c * GBLK;
  const int rowbase = p * GROWS;
  const int tid = threadIdx.x;
  const int q = tid / GROWS;          // 0..3, uniform per wave (192 = 3*64)
  const int r = tid - q * GROWS;      // 0..191
  const int grow = rowbase + r;

  // ---- one-time weight preload (coalesced via wT; 64 VGPRs/lane) ----
  float4 wv[16];
#pragma unroll
  for (int i = 0; i < 16; ++i) {
    const int col = q * 64 + 4 * i;
    wv[i].x = wT[(col + 0) * 768 + grow];
    wv[i].y = wT[(col + 1) * 768 + grow];
    wv[i].z = wT[(col + 2) * 768 + grow];
    wv[i].w = wT[(col + 3) * 768 + grow];
  }
#pragma unroll
  for (int i = 0; i < 16; ++i)
    asm volatile("" : "+v"(wv[i].x), "+v"(wv[i].y), "+v"(wv[i].z), "+v"(wv[i].w));
  const float bh = b_hh[grow];

  float hold = 0.f;
  if (tid < 256) hs[tid] = 0.f;
  float* Gc = G + c * 1536;
  unsigned sigma = 0;

  // ================= story: 32 chunks x 20 steps =================
  for (int b = 0; b < NB; ++b) {
    __syncthreads();                       // stage-reuse guard (+h init, b=0)
    const int srow0 = b * 1000 + c * SEN;
    for (int idx = tid; idx < SEN * 256; idx += GTHR) {
      const int tt = idx >> 8, d = idx & 255;
      st_gn[idx] = gi[(size_t)(srow0 + tt) * 768 + 512 + d];
    }
    if (rowbase < 512) {
      for (int idx = tid; idx < SEN * GROWS; idx += GTHR) {
        const int tt = idx / GROWS, d = idx - tt * GROWS;
        const int gg = rowbase + d;
        st_own[idx] = (gg < 512) ? gi[(size_t)(srow0 + tt) * 768 + gg] : 0.f;
      }
    }
    const int cs = idxI[b * MEMN + c];
    __syncthreads();

    for (int t = 0; t < SEN; ++t) {
      ++sigma;
      const float4* h4p = (const float4*)hs + q * 16;
      float dot = 0.f;
#pragma unroll
      for (int i = 0; i < 16; ++i) {
        float4 h4 = h4p[i];
        dot += wv[i].x*h4.x + wv[i].y*h4.y + wv[i].z*h4.z + wv[i].w*h4.w;
      }
      part[tid] = dot;
      __syncthreads();
      if (tid < GROWS) {
        float S = part[tid] + part[GROWS+tid] + part[2*GROWS+tid] + part[3*GROWS+tid] + bh;
        if (grow < 512) S += st_own[t*GROWS+tid];    // r,z rows add gi here
        Gc[(sigma & 1) * 768 + rowbase + tid] = S;
      }
      __threadfence();
      __syncthreads();
      if (tid == 0) {
        __hip_atomic_fetch_add(&scnt[c], 1u, __ATOMIC_RELEASE, __HIP_MEMORY_SCOPE_AGENT);
        while (__hip_atomic_load(&scnt[c], __ATOMIC_ACQUIRE, __HIP_MEMORY_SCOPE_AGENT) < (unsigned)GBLK * sigma)
          __builtin_amdgcn_s_sleep(1);
      }
      __syncthreads();
      if (tid < 256) {
        const float* gb = Gc + (sigma & 1) * 768;
        float Sr = __hip_atomic_load(gb + tid,       __ATOMIC_RELAXED, __HIP_MEMORY_SCOPE_AGENT);
        float Sz = __hip_atomic_load(gb + 256 + tid, __ATOMIC_RELAXED, __HIP_MEMORY_SCOPE_AGENT);
        float Sn = __hip_atomic_load(gb + 512 + tid, __ATOMIC_RELAXED, __HIP_MEMORY_SCOPE_AGENT);
        float gn = st_gn[t*256+tid];
        float rg = 1.f / (1.f + __expf(-Sr));
        float zg = 1.f / (1.f + __expf(-Sz));
        float xn = gn + rg * Sn;
        xn = fminf(fmaxf(xn, -15.f), 15.f);
        float e2 = __expf(-2.f * xn);
        float ng = (1.f - e2) / (1.f + e2);
        float hnew = (1.f - zg) * ng + zg * hold;
        hold = hnew;
        hs[tid] = hnew;
        if (t == cs && p == 0) slot_out[(b * MEMN + c) * 256 + tid] = hnew;
      }
      __syncthreads();
    }
  }

  // ================= query: chains 0..31 reuse their 4 blocks =================
  if (c < NB) {
    __syncthreads();
    hold = 0.f;
    if (tid < 256) hs[tid] = 0.f;
    const int srow0 = 32000 + c * SEN;
    for (int idx = tid; idx < SEN * 256; idx += GTHR) {
      const int tt = idx >> 8, d = idx & 255;
      st_gn[idx] = gi[(size_t)(srow0 + tt) * 768 + 512 + d];
    }
    if (rowbase < 512) {
      for (int idx = tid; idx < SEN * GROWS; idx += GTHR) {
        const int tt = idx / GROWS, d = idx - tt * GROWS;
        const int gg = rowbase + d;
        st_own[idx] = (gg < 512) ? gi[(size_t)(srow0 + tt) * 768 + gg] : 0.f;
      }
    }
    const int cs = idxI[1600 + c];
    float* Gq = GQ + c * 1536;
    __syncthreads();
    unsigned sq = 0;
    for (int t = 0; t < SEN; ++t) {
      ++sq;
      const float4* h4p = (const float4*)hs + q * 16;
      float dot = 0.f;
#pragma unroll
      for (int i = 0; i < 16; ++i) {
        float4 h4 = h4p[i];
        dot += wv[i].x*h4.x + wv[i].y*h4.y + wv[i].z*h4.z + wv[i].w*h4.w;
      }
      part[tid] = dot;
      __syncthreads();
      if (tid < GROWS) {
        float S = part[tid] + part[GROWS+tid] + part[2*GROWS+tid] + part[3*GROWS+tid] + bh;
        if (grow < 512) S += st_own[t*GROWS+tid];
        Gq[(sq & 1) * 768 + rowbase + tid] = S;
      }
      __threadfence();
      __syncthreads();
      if (tid == 0) {
        __hip_atomic_fetch_add(&qcnt[c], 1u, __ATOMIC_RELEASE, __HIP_MEMORY_SCOPE_AGENT);
        while (__hip_atomic_load(&qcnt[c], __ATOMIC_ACQUIRE, __HIP_MEMORY_SCOPE_AGENT) < (unsigned)GBLK * sq)
          __builtin_amdgcn_s_sleep(1);
      }
      __syncthreads();
      if (tid < 256) {
        const float* gb = Gq + (sq & 1) * 768;
        float Sr = __hip_atomic_load(gb + tid,       __ATOMIC_RELAXED, __HIP_MEMORY_SCOPE_AGENT);
        float Sz = __hip_atomic_load(gb + 256 + tid, __ATOMIC_RELAXED, __HIP_MEMORY_SCOPE_AGENT);
        float Sn = __hip_atomic_load(gb + 512 + tid, __ATOMIC_RELAXED, __HIP_MEMORY_SCOPE_AGENT);
        float gn = st_gn[t*256+tid];
        float rg = 1.f / (1.f + __expf(-Sr));
        float zg = 1.f / (1.f + __expf(-Sz));
        float xn = gn + rg * Sn;
        xn = fminf(fmaxf(xn, -15.f), 15.f);
        float e2 = __expf(-2.f * xn);
        float ng = (1.f - e2) / (1.f + e2);
        float hnew = (1.f - zg) * ng + zg * hold;
        hold = hnew;
        hs[tid] = hnew;
        if (t == cs && p == 0) rq_out[c * 256 + tid] = hnew;
      }
      __syncthreads();
    }
  }
}

// ---------------------------------------------------------------------------
// Multi-hop attention, one block per batch element.
// ---------------------------------------------------------------------------
__device__ __forceinline__ float gemv256(const float* __restrict__ WT,
                                         const float* __restrict__ xs, int j)
{
  float acc = 0.f;
#pragma unroll 64
  for (int k = 0; k < 256; ++k) acc += xs[k] * WT[k * 256 + j];
  return acc;
}

__global__ __launch_bounds__(256) void k_hops(
    const float* __restrict__ rq, const float* __restrict__ kvb,
    const float* __restrict__ wqT, const float* __restrict__ bq,
    const float* __restrict__ woT, const float* __restrict__ bo,
    const float* __restrict__ f1T, const float* __restrict__ fb1,
    const float* __restrict__ f2T, const float* __restrict__ fb2,
    float* __restrict__ mb)
{
  const int b = blockIdx.x, j = threadIdx.x;
  __shared__ float lk[50 * 259];
  __shared__ float lv[50 * 259];
  __shared__ float xs[256], tb[256], qs[256], avs[256], ob[256], asc[256];

  for (int idx = j; idx < 12800; idx += 256) {
    int m = idx >> 8, d = idx & 255;
    lk[m * 259 + d] = kvb[(b * MEMN + m) * 512 + d];
    lv[m * 259 + d] = kvb[(b * MEMN + m) * 512 + 256 + d];
  }
  xs[j] = rq[b * 256 + j];
  __syncthreads();

  float v = fmaxf(gemv256(f1T, xs, j) + fb1[j], 0.f);
  __syncthreads(); tb[j] = v; __syncthreads();
  v = gemv256(f2T, tb, j) + fb2[j];
  __syncthreads(); xs[j] = v; __syncthreads();

  for (int hop = 0; hop < 3; ++hop) {
    v = gemv256(wqT, xs, j) + bq[j];
    __syncthreads(); qs[j] = v; __syncthreads();

    const int w = j >> 6, l = j & 63;
    float sc = -1e30f;
    if (l < MEMN) {
      sc = 0.f;
#pragma unroll 16
      for (int d = 0; d < 64; ++d) sc += qs[w * 64 + d] * lk[l * 259 + w * 64 + d];
      sc *= 0.125f;  // 1/sqrt(dk=64)
    }
    float mx = sc;
#pragma unroll
    for (int off = 32; off > 0; off >>= 1) mx = fmaxf(mx, __shfl_xor(mx, off));
    float e = (l < MEMN) ? __expf(sc - mx) : 0.f;
    float sm = e;
#pragma unroll
    for (int off = 32; off > 0; off >>= 1) sm += __shfl_xor(sm, off);
    float a = e / sm;
    __syncthreads(); asc[j] = a; __syncthreads();

    float av = 0.f;
#pragma unroll 10
    for (int m = 0; m < MEMN; ++m) av += asc[w * 64 + m] * lv[m * 259 + w * 64 + l];
    __syncthreads(); avs[j] = av; __syncthreads();

    v = gemv256(woT, avs, j) + bo[j];
    mb[(b * 3 + hop) * 256 + j] = v;
    if (hop < 2) {
      __syncthreads(); ob[j] = v; __syncthreads();
      v = fmaxf(gemv256(f1T, ob, j) + fb1[j], 0.f);
      __syncthreads(); tb[j] = v; __syncthreads();
      v = gemv256(f2T, tb, j) + fb2[j];
      __syncthreads(); xs[j] = v; __syncthreads();
    }
  }
}

// reasoning[b][j] = sum_p relu(t2)[b*9+p][j]  (t2 already relu'd)
__global__ void k_rsum(const float* __restrict__ t2, float* __restrict__ rs)
{
  int gid = blockIdx.x * TPB + threadIdx.x;
  int b = gid / 768, jj = gid - b * 768;
  float acc = 0.f;
#pragma unroll
  for (int p = 0; p < 9; ++p) acc += t2[(b * 9 + p) * 768 + jj];
  rs[b * 768 + jj] = acc;
}

// out[32][100000] = reasoning @ v_w^T. 64 vocab cols per block, K chunked 128.
__global__ __launch_bounds__(256) void k_vocab(const float* __restrict__ rs,
                                               const float* __restrict__ vw,
                                               float* __restrict__ out)
{
  __shared__ float vt[64 * 132];
  __shared__ float rt[32 * 132];
  const int c0 = blockIdx.x * 64;
  const int tx = threadIdx.x & 15, ty = threadIdx.x >> 4;
  float acc[2][4] = {{0.f,0.f,0.f,0.f},{0.f,0.f,0.f,0.f}};

  for (int k0 = 0; k0 < 768; k0 += 128) {
    for (int idx = threadIdx.x; idx < 2048; idx += 256) {
      int r = idx >> 5, q = idx & 31;
      int col = c0 + r;
      float4 v4 = make_float4(0.f, 0.f, 0.f, 0.f);
      if (col < VOC) v4 = ((const float4*)(vw + (size_t)col * 768 + k0))[q];
      *(float4*)&vt[r * 132 + q * 4] = v4;
    }
    for (int idx = threadIdx.x; idx < 1024; idx += 256) {
      int r = idx >> 5, q = idx & 31;
      float4 v4 = ((const float4*)(rs + r * 768 + k0))[q];
      *(float4*)&rt[r * 132 + q * 4] = v4;
    }
    __syncthreads();
#pragma unroll 4
    for (int kk = 0; kk < 128; ++kk) {
      float a0 = rt[(ty * 2 + 0) * 132 + kk];
      float a1 = rt[(ty * 2 + 1) * 132 + kk];
#pragma unroll
      for (int cc = 0; cc < 4; ++cc) {
        float bv_ = vt[(tx + cc * 16) * 132 + kk];
        acc[0][cc] += a0 * bv_;
        acc[1][cc] += a1 * bv_;
      }
    }
    __syncthreads();
  }
#pragma unroll
  for (int rr = 0; rr < 2; ++rr)
#pragma unroll
    for (int cc = 0; cc < 4; ++cc) {
      int cx = c0 + tx + cc * 16;
      if (cx < VOC) out[(ty * 2 + rr) * VOC + cx] = acc[rr][cc];
    }
}

// ---------------------------------------------------------------------------
extern "C" void kernel_launch(void* const* d_in, const int* in_sizes, int n_in,
                              void* d_out, int out_size, void* d_ws, size_t ws_size,
                              hipStream_t stream)
{
  const int*   story = (const int*)d_in[0];
  const int*   query = (const int*)d_in[1];
  const float* embed = (const float*)d_in[2];
  const float* w_ih  = (const float*)d_in[3];
  const float* w_hh  = (const float*)d_in[4];
  const float* b_ih  = (const float*)d_in[5];
  const float* b_hh  = (const float*)d_in[6];
  const float* ft_w1 = (const float*)d_in[7];
  const float* ft_b1 = (const float*)d_in[8];
  const float* ft_w2 = (const float*)d_in[9];
  const float* ft_b2 = (const float*)d_in[10];
  const float* wq    = (const float*)d_in[11];
  const float* bq    = (const float*)d_in[12];
  const float* wk    = (const float*)d_in[13];
  const float* bk    = (const float*)d_in[14];
  const float* wv    = (const float*)d_in[15];
  const float* bv    = (const float*)d_in[16];
  const float* wo    = (const float*)d_in[17];
  const float* bo    = (const float*)d_in[18];
  const float* g_w1  = (const float*)d_in[19];
  const float* g_b1  = (const float*)d_in[20];
  const float* g_w2  = (const float*)d_in[21];
  const float* g_b2  = (const float*)d_in[22];
  const float* v_w   = (const float*)d_in[23];
  float* out = (float*)d_out;
  float* ws  = (float*)d_ws;

  // 1) transposes / biases / seqend indices / counter zero
  k_setup<<<7689, TPB, 0, stream>>>(w_ih, w_hh, wk, wv, wq, wo, ft_w1, ft_w2,
                                    g_w1, g_w2, bk, bv, story, query, ws);
  // 2) gi = embed[tokens] @ w_ih^T + b_ih
  k_gemm<1,128><<<dim3(255, 6), TPB, 0, stream>>>(
      nullptr, ws + WTIH_OFF, b_ih, ws + GI_OFF, 32640, 768, 256, 0,
      story, query, embed, nullptr, nullptr);
  // 3) GRU: 50 chains x 4 blocks (story), then query on chains 0..31
  k_gru<<<MEMN * GBLK, GTHR, 0, stream>>>(
      ws + GI_OFF, ws + WTHH_OFF, b_hh, (const int*)(ws + IDX_OFF),
      ws + SLOT_OFF, ws + RQ_OFF, ws + G_OFF, ws + GQ_OFF,
      (unsigned int*)(ws + SCNT_OFF), (unsigned int*)(ws + SCNT_OFF) + 50);
  // 4) k/v projections
  k_gemm<0,128><<<dim3(13, 4), TPB, 0, stream>>>(
      ws + SLOT_OFF, ws + KVT_OFF, ws + BKV_OFF, ws + KVB_OFF, 1600, 512, 256, 0,
      nullptr, nullptr, nullptr, nullptr, nullptr);
  // 5) 3 attention hops + f_t chain
  k_hops<<<NB, TPB, 0, stream>>>(ws + RQ_OFF, ws + KVB_OFF,
                                 ws + WQT_OFF, bq, ws + WOT_OFF, bo,
                                 ws + F1T_OFF, ft_b1, ws + F2T_OFF, ft_b2,
                                 ws + MB_OFF);
  // 6) reasoning layer 1
  k_gemm<2,32><<<dim3(9, 6), TPB, 0, stream>>>(
      nullptr, ws + G1T_OFF, g_b1, ws + T1_OFF, 288, 768, 768, 1,
      nullptr, nullptr, nullptr, ws + MB_OFF, ws + RQ_OFF);
  // 7) reasoning layer 2
  k_gemm<0,32><<<dim3(9, 6), TPB, 0, stream>>>(
      ws + T1_OFF, ws + G2T_OFF, g_b2, ws + T2_OFF, 288, 768, 768, 1,
      nullptr, nullptr, nullptr, nullptr, nullptr);
  // 8) sum over 9 pairs
  k_rsum<<<96, TPB, 0, stream>>>(ws + T2_OFF, ws + RS_OFF);
  // 9) logits = reasoning @ v_w^T
  k_vocab<<<(VOC + 63) / 64, TPB, 0, stream>>>(ws + RS_OFF, v_w, out);
}